// Round 1
// baseline (814.691 us; speedup 1.0000x reference)
//
#include <hip/hip_runtime.h>
#include <float.h>
#include <math.h>

constexpr int NN  = 30000;   // nodes
constexpr int EE  = 300000;  // edges before self-loops
constexpr int GG  = 1024;    // graphs
constexpr int HID = 256;
constexpr int NH  = 8;       // heads
constexpr int EP  = EE + NN; // edges incl self-loops

// ---------------- CSR build ----------------
__global__ void k_hist(const int* __restrict__ edst, int* __restrict__ cnt) {
    int i = blockIdx.x * blockDim.x + threadIdx.x;
    if (i >= EP) return;
    int d = (i < EE) ? edst[i] : (i - EE);
    atomicAdd(&cnt[d], 1);
}

__global__ void k_scan(const int* __restrict__ cnt, int* __restrict__ indptr) {
    __shared__ int wtot[16];
    __shared__ int carry_s;
    int tid = threadIdx.x;
    int lane = tid & 63, wid = tid >> 6;
    if (tid == 0) carry_s = 0;
    __syncthreads();
    for (int base = 0; base < NN; base += 1024) {
        int i = base + tid;
        int v = (i < NN) ? cnt[i] : 0;
        int incl = v;
        #pragma unroll
        for (int off = 1; off < 64; off <<= 1) {
            int t = __shfl_up(incl, off, 64);
            if (lane >= off) incl += t;
        }
        if (lane == 63) wtot[wid] = incl;
        __syncthreads();
        int wpre = 0;
        for (int w = 0; w < wid; ++w) wpre += wtot[w];
        int c = carry_s;
        if (i < NN) indptr[i] = c + wpre + incl - v;  // exclusive
        int tot = 0;
        for (int w = 0; w < 16; ++w) tot += wtot[w];
        __syncthreads();
        if (tid == 0) carry_s = c + tot;
        __syncthreads();
    }
    if (tid == 0) indptr[NN] = carry_s;
}

__global__ void k_fill(const int* __restrict__ esrc, const int* __restrict__ edst,
                       const int* __restrict__ indptr, int* __restrict__ cursor,
                       int* __restrict__ srcs) {
    int i = blockIdx.x * blockDim.x + threadIdx.x;
    if (i >= EP) return;
    int d, s;
    if (i < EE) { d = edst[i]; s = esrc[i]; } else { d = i - EE; s = i - EE; }
    int pos = indptr[d] + atomicAdd(&cursor[d], 1);
    srcs[pos] = s;
}

// deterministic order regardless of atomic scatter order
__global__ void k_sortseg(int* __restrict__ srcs, const int* __restrict__ indptr) {
    int node = blockIdx.x * blockDim.x + threadIdx.x;
    if (node >= NN) return;
    int b = indptr[node], e = indptr[node + 1];
    for (int i = b + 1; i < e; ++i) {
        int v = srcs[i];
        int j = i - 1;
        while (j >= b && srcs[j] > v) { srcs[j + 1] = srcs[j]; --j; }
        srcs[j + 1] = v;
    }
}

__global__ void k_starts(const int* __restrict__ batch, int* __restrict__ starts) {
    int i = blockIdx.x * blockDim.x + threadIdx.x;
    if (i >= NN) return;
    int b = batch[i];
    if (i == 0 || batch[i - 1] != b) starts[b] = i;
    if (i == NN - 1) starts[GG] = NN;
}

// ---------------- embedding with max_norm=1 ----------------
__global__ void k_embed(const int* __restrict__ ids, const float* __restrict__ emb,
                        float* __restrict__ X) {
    int w = (blockIdx.x * blockDim.x + threadIdx.x) >> 6;
    if (w >= NN) return;
    int lane = threadIdx.x & 63;
    const float4 v = *(const float4*)(emb + (size_t)ids[w] * HID + lane * 4);
    float ss = v.x * v.x + v.y * v.y + v.z * v.z + v.w * v.w;
    #pragma unroll
    for (int off = 32; off >= 1; off >>= 1) ss += __shfl_xor(ss, off, 64);
    float nrm = sqrtf(ss);
    float sc = fminf(1.0f, 1.0f / (nrm + 1e-12f));
    float4 o;
    o.x = v.x * sc; o.y = v.y * sc; o.z = v.z * sc; o.w = v.w * sc;
    *(float4*)(X + (size_t)w * HID + lane * 4) = o;
}

// ---------------- fp32 GEMM: O[M,256] = X[M,256] @ W[256,256]^T ----------------
// TN layout: O[m][n] = sum_k X[m][k]*W[n][k]  (both k-contiguous)
#define GBM 64
#define GBN 64
#define GBK 64
#define LDST 68   // floats; rows 272B -> 16B-aligned, conflict-light

__global__ __launch_bounds__(256) void k_gemm(const float* __restrict__ X,
                                              const float* __restrict__ W,
                                              float* __restrict__ O, int M) {
    __shared__ float aT[GBK][LDST];
    __shared__ float bT[GBK][LDST];
    int m0 = blockIdx.x * GBM;
    int n0 = blockIdx.y * GBN;
    int tid = threadIdx.x;
    int cq = tid & 3;       // 0..3: k-quarter for loads
    int r  = tid >> 2;      // 0..63: row within tile for loads
    int tx = tid & 15, ty = tid >> 4;
    float acc[4][4] = {{0.f}};
    int rowa = m0 + r;
    bool avalid = rowa < M;
    const float* xrow = X + (size_t)rowa * HID;
    const float* wrow = W + (size_t)(n0 + r) * HID;
    for (int kk = 0; kk < HID; kk += GBK) {
        #pragma unroll
        for (int i = 0; i < 4; ++i) {
            int k = cq * 4 + i * 16;
            float4 va;
            if (avalid) va = *(const float4*)(xrow + kk + k);
            else { va.x = va.y = va.z = va.w = 0.f; }
            float4 vb = *(const float4*)(wrow + kk + k);
            aT[k + 0][r] = va.x; aT[k + 1][r] = va.y; aT[k + 2][r] = va.z; aT[k + 3][r] = va.w;
            bT[k + 0][r] = vb.x; bT[k + 1][r] = vb.y; bT[k + 2][r] = vb.z; bT[k + 3][r] = vb.w;
        }
        __syncthreads();
        #pragma unroll 8
        for (int k = 0; k < GBK; ++k) {
            float4 a4 = *(const float4*)&aT[k][ty * 4];
            float4 b4 = *(const float4*)&bT[k][tx * 4];
            float av[4] = {a4.x, a4.y, a4.z, a4.w};
            float bv[4] = {b4.x, b4.y, b4.z, b4.w};
            #pragma unroll
            for (int i = 0; i < 4; ++i)
                #pragma unroll
                for (int j = 0; j < 4; ++j)
                    acc[i][j] = fmaf(av[i], bv[j], acc[i][j]);
        }
        __syncthreads();
    }
    #pragma unroll
    for (int i = 0; i < 4; ++i) {
        int row = m0 + ty * 4 + i;
        if (row < M) {
            float4 o;
            o.x = acc[i][0]; o.y = acc[i][1]; o.z = acc[i][2]; o.w = acc[i][3];
            *(float4*)(O + (size_t)row * HID + n0 + tx * 4) = o;
        }
    }
}

// ---------------- attention logits: es/ed[n][h] = <h[n,h,:], a> ----------------
__global__ void k_scores(const float* __restrict__ H, const float* __restrict__ a_src,
                         const float* __restrict__ a_dst, float* __restrict__ es,
                         float* __restrict__ ed) {
    int w = (blockIdx.x * blockDim.x + threadIdx.x) >> 6;
    if (w >= NN) return;
    int lane = threadIdx.x & 63;
    int head = lane >> 3;       // channels [lane*4, lane*4+4) -> head = lane/8
    int sub = lane & 7;
    float4 h = *(const float4*)(H + (size_t)w * HID + lane * 4);
    float4 as4 = *(const float4*)(a_src + head * 32 + sub * 4);
    float4 ad4 = *(const float4*)(a_dst + head * 32 + sub * 4);
    float ps = h.x * as4.x + h.y * as4.y + h.z * as4.z + h.w * as4.w;
    float pd = h.x * ad4.x + h.y * ad4.y + h.z * ad4.z + h.w * ad4.w;
    #pragma unroll
    for (int off = 1; off < 8; off <<= 1) {
        ps += __shfl_xor(ps, off, 64);
        pd += __shfl_xor(pd, off, 64);
    }
    if (sub == 0) {
        es[w * NH + head] = ps;
        ed[w * NH + head] = pd;
    }
}

// ---------------- segment softmax + weighted aggregate + bias + relu ----------------
__global__ __launch_bounds__(256) void k_aggregate(const float* __restrict__ H,
                                                   const float* __restrict__ es,
                                                   const float* __restrict__ ed,
                                                   const int* __restrict__ indptr,
                                                   const int* __restrict__ srcs,
                                                   const float* __restrict__ bias,
                                                   float* __restrict__ Xout) {
    int node = (blockIdx.x * blockDim.x + threadIdx.x) >> 6;
    if (node >= NN) return;
    int lane = threadIdx.x & 63;
    int head = lane >> 3;
    int b0 = indptr[node], e0 = indptr[node + 1];
    float edv = ed[node * NH + head];
    float m = -FLT_MAX;
    for (int j = b0; j < e0; ++j) {
        int s = srcs[j];
        float e = es[s * NH + head] + edv;
        e = (e > 0.f) ? e : 0.2f * e;
        m = fmaxf(m, e);
    }
    float sum = 0.f;
    float ax = 0.f, ay = 0.f, az = 0.f, aw = 0.f;
    for (int j = b0; j < e0; ++j) {
        int s = srcs[j];
        float e = es[s * NH + head] + edv;
        e = (e > 0.f) ? e : 0.2f * e;
        float wgt = expf(e - m);
        sum += wgt;
        float4 h = *(const float4*)(H + (size_t)s * HID + lane * 4);
        ax = fmaf(wgt, h.x, ax);
        ay = fmaf(wgt, h.y, ay);
        az = fmaf(wgt, h.z, az);
        aw = fmaf(wgt, h.w, aw);
    }
    float inv = 1.f / (sum + 1e-16f);
    float4 bv = *(const float4*)(bias + lane * 4);
    float4 o;
    o.x = fmaxf(fmaf(ax, inv, bv.x), 0.f);
    o.y = fmaxf(fmaf(ay, inv, bv.y), 0.f);
    o.z = fmaxf(fmaf(az, inv, bv.z), 0.f);
    o.w = fmaxf(fmaf(aw, inv, bv.w), 0.f);
    *(float4*)(Xout + (size_t)node * HID + lane * 4) = o;
}

// ---------------- per-graph max pool + linear head ----------------
__global__ void k_pool(const float* __restrict__ X, const int* __restrict__ starts,
                       const float* __restrict__ fw, const float* __restrict__ fb,
                       float* __restrict__ out) {
    int g = (blockIdx.x * blockDim.x + threadIdx.x) >> 6;
    if (g >= GG) return;
    int lane = threadIdx.x & 63;
    int s = starts[g], e = starts[g + 1];
    float mx0 = -FLT_MAX, mx1 = -FLT_MAX, mx2 = -FLT_MAX, mx3 = -FLT_MAX;
    for (int n = s; n < e; ++n) {
        float4 v = *(const float4*)(X + (size_t)n * HID + lane * 4);
        mx0 = fmaxf(mx0, v.x); mx1 = fmaxf(mx1, v.y);
        mx2 = fmaxf(mx2, v.z); mx3 = fmaxf(mx3, v.w);
    }
    float4 w = *(const float4*)(fw + lane * 4);
    float t = mx0 * w.x + mx1 * w.y + mx2 * w.z + mx3 * w.w;
    #pragma unroll
    for (int off = 32; off >= 1; off >>= 1) t += __shfl_xor(t, off, 64);
    if (lane == 0) out[g] = t + fb[0];
}

// ---------------- launcher ----------------
extern "C" void kernel_launch(void* const* d_in, const int* in_sizes, int n_in,
                              void* d_out, int out_size, void* d_ws, size_t ws_size,
                              hipStream_t stream) {
    const int* x_ids = (const int*)d_in[0];
    const int* eidx  = (const int*)d_in[1];   // [2, E] row-major: [0..E)=src, [E..2E)=dst
    const int* batch = (const int*)d_in[2];
    const float* emb = (const float*)d_in[3];
    const float* fw  = (const float*)d_in[4];
    const float* fb  = (const float*)d_in[5];
    const float* Wl[5], *asl[5], *adl[5], *bl[5];
    for (int l = 0; l < 5; ++l) {
        Wl[l]  = (const float*)d_in[6 + 4 * l];
        asl[l] = (const float*)d_in[7 + 4 * l];
        adl[l] = (const float*)d_in[8 + 4 * l];
        bl[l]  = (const float*)d_in[9 + 4 * l];
    }

    char* ws = (char*)d_ws;
    size_t off = 0;
    auto alloc = [&](size_t bytes) {
        void* p = ws + off;
        off = (off + bytes + 255) & ~(size_t)255;
        return p;
    };
    float* P    = (float*)alloc((size_t)NN * HID * 4);  // x buffer
    float* Q    = (float*)alloc((size_t)NN * HID * 4);  // h buffer
    float* es   = (float*)alloc((size_t)NN * NH * 4);
    float* ed   = (float*)alloc((size_t)NN * NH * 4);
    int* cnt    = (int*)alloc((size_t)NN * 4);
    int* cursor = (int*)alloc((size_t)NN * 4);
    int* indptr = (int*)alloc((size_t)(NN + 1) * 4);
    int* srcs   = (int*)alloc((size_t)EP * 4);
    int* starts = (int*)alloc((size_t)(GG + 1) * 4);
    (void)ws_size; (void)in_sizes; (void)n_in; (void)out_size;

    hipMemsetAsync(cnt, 0, (size_t)NN * 4, stream);
    hipMemsetAsync(cursor, 0, (size_t)NN * 4, stream);

    k_hist<<<(EP + 255) / 256, 256, 0, stream>>>(eidx + EE, cnt);
    k_scan<<<1, 1024, 0, stream>>>(cnt, indptr);
    k_fill<<<(EP + 255) / 256, 256, 0, stream>>>(eidx, eidx + EE, indptr, cursor, srcs);
    k_sortseg<<<(NN + 255) / 256, 256, 0, stream>>>(srcs, indptr);
    k_starts<<<(NN + 255) / 256, 256, 0, stream>>>(batch, starts);
    k_embed<<<NN / 4, 256, 0, stream>>>(x_ids, emb, P);

    for (int l = 0; l < 5; ++l) {
        dim3 gg((NN + GBM - 1) / GBM, HID / GBN);
        k_gemm<<<gg, 256, 0, stream>>>(P, Wl[l], Q, NN);
        k_scores<<<NN / 4, 256, 0, stream>>>(Q, asl[l], adl[l], es, ed);
        k_aggregate<<<NN / 4, 256, 0, stream>>>(Q, es, ed, indptr, srcs, bl[l], P);
    }
    k_pool<<<GG / 4, 256, 0, stream>>>(P, starts, fw, fb, (float*)d_out);
}

// Round 2
// 552.613 us; speedup vs baseline: 1.4743x; 1.4743x over previous
//
#include <hip/hip_runtime.h>
#include <float.h>
#include <math.h>

constexpr int NN  = 30000;   // nodes
constexpr int EE  = 300000;  // edges before self-loops
constexpr int GG  = 1024;    // graphs
constexpr int HID = 256;
constexpr int NH  = 8;       // heads
constexpr int EP  = EE + NN; // edges incl self-loops
constexpr int NP  = 30080;   // padded rows: 235 * 128

typedef short bf16x8 __attribute__((ext_vector_type(8)));
typedef float f32x4 __attribute__((ext_vector_type(4)));

__device__ __forceinline__ void gload_lds16(const void* g, void* l) {
    __builtin_amdgcn_global_load_lds(
        (const __attribute__((address_space(1))) unsigned int*)g,
        (__attribute__((address_space(3))) unsigned int*)l, 16, 0, 0);
}

__device__ __forceinline__ void f2hilo(float x, unsigned short& h, unsigned short& l) {
    unsigned u = __float_as_uint(x);
    h = (unsigned short)(u >> 16);                       // truncated hi
    float hv = __uint_as_float(u & 0xFFFF0000u);
    float r = x - hv;                                    // exact residual
    unsigned v = __float_as_uint(r);
    unsigned rnd = ((v >> 16) & 1u) + 0x7FFFu;           // RNE to bf16
    l = (unsigned short)((v + rnd) >> 16);
}

__device__ __forceinline__ float bf2f(unsigned short u) {
    return __uint_as_float(((unsigned)u) << 16);
}

// ---------------- CSR build ----------------
__global__ void k_hist(const int* __restrict__ edst, int* __restrict__ cnt) {
    int i = blockIdx.x * blockDim.x + threadIdx.x;
    if (i >= EP) return;
    int d = (i < EE) ? edst[i] : (i - EE);
    atomicAdd(&cnt[d], 1);
}

__global__ void k_scan(const int* __restrict__ cnt, int* __restrict__ indptr) {
    __shared__ int wtot[16];
    __shared__ int carry_s;
    int tid = threadIdx.x;
    int lane = tid & 63, wid = tid >> 6;
    if (tid == 0) carry_s = 0;
    __syncthreads();
    for (int base = 0; base < NN; base += 1024) {
        int i = base + tid;
        int v = (i < NN) ? cnt[i] : 0;
        int incl = v;
        #pragma unroll
        for (int off = 1; off < 64; off <<= 1) {
            int t = __shfl_up(incl, off, 64);
            if (lane >= off) incl += t;
        }
        if (lane == 63) wtot[wid] = incl;
        __syncthreads();
        int wpre = 0;
        for (int w = 0; w < wid; ++w) wpre += wtot[w];
        int c = carry_s;
        if (i < NN) indptr[i] = c + wpre + incl - v;  // exclusive
        int tot = 0;
        for (int w = 0; w < 16; ++w) tot += wtot[w];
        __syncthreads();
        if (tid == 0) carry_s = c + tot;
        __syncthreads();
    }
    if (tid == 0) indptr[NN] = carry_s;
}

__global__ void k_fill(const int* __restrict__ esrc, const int* __restrict__ edst,
                       const int* __restrict__ indptr, int* __restrict__ cursor,
                       int* __restrict__ srcs) {
    int i = blockIdx.x * blockDim.x + threadIdx.x;
    if (i >= EP) return;
    int d, s;
    if (i < EE) { d = edst[i]; s = esrc[i]; } else { d = i - EE; s = i - EE; }
    int pos = indptr[d] + atomicAdd(&cursor[d], 1);
    srcs[pos] = s;
}

__global__ void k_sortseg(int* __restrict__ srcs, const int* __restrict__ indptr) {
    int node = blockIdx.x * blockDim.x + threadIdx.x;
    if (node >= NN) return;
    int b = indptr[node], e = indptr[node + 1];
    for (int i = b + 1; i < e; ++i) {
        int v = srcs[i];
        int j = i - 1;
        while (j >= b && srcs[j] > v) { srcs[j + 1] = srcs[j]; --j; }
        srcs[j + 1] = v;
    }
}

__global__ void k_starts(const int* __restrict__ batch, int* __restrict__ starts) {
    int i = blockIdx.x * blockDim.x + threadIdx.x;
    if (i >= NN) return;
    int b = batch[i];
    if (i == 0 || batch[i - 1] != b) starts[b] = i;
    if (i == NN - 1) starts[GG] = NN;
}

// ---------------- weight split fp32 -> bf16 hi/lo ----------------
__global__ void k_wconv(const float* __restrict__ W1, const float* __restrict__ W2,
                        const float* __restrict__ W3, const float* __restrict__ W4,
                        const float* __restrict__ W5,
                        unsigned short* __restrict__ Whi, unsigned short* __restrict__ Wlo) {
    int i = blockIdx.x * blockDim.x + threadIdx.x;  // 0..65535
    int l = blockIdx.y;
    const float* W = (l == 0) ? W1 : (l == 1) ? W2 : (l == 2) ? W3 : (l == 3) ? W4 : W5;
    unsigned short h, lo;
    f2hilo(W[i], h, lo);
    Whi[(size_t)l * 65536 + i] = h;
    Wlo[(size_t)l * 65536 + i] = lo;
}

// ---------------- embedding with max_norm=1 -> hi/lo ----------------
__global__ void k_embed(const int* __restrict__ ids, const float* __restrict__ emb,
                        unsigned short* __restrict__ Phi, unsigned short* __restrict__ Plo) {
    int w = (blockIdx.x * blockDim.x + threadIdx.x) >> 6;
    if (w >= NN) return;
    int lane = threadIdx.x & 63;
    const float4 v = *(const float4*)(emb + (size_t)ids[w] * HID + lane * 4);
    float ss = v.x * v.x + v.y * v.y + v.z * v.z + v.w * v.w;
    #pragma unroll
    for (int off = 32; off >= 1; off >>= 1) ss += __shfl_xor(ss, off, 64);
    float nrm = sqrtf(ss);
    float sc = fminf(1.0f, 1.0f / (nrm + 1e-12f));
    float o[4] = {v.x * sc, v.y * sc, v.z * sc, v.w * sc};
    ushort4 hv, lv;
    f2hilo(o[0], hv.x, lv.x); f2hilo(o[1], hv.y, lv.y);
    f2hilo(o[2], hv.z, lv.z); f2hilo(o[3], hv.w, lv.w);
    *(ushort4*)(Phi + (size_t)w * HID + lane * 4) = hv;
    *(ushort4*)(Plo + (size_t)w * HID + lane * 4) = lv;
}

// ---------------- split-bf16 MFMA GEMM: O[M,256] = (hi+lo)X @ (hi+lo)W^T ----------------
// m97-style: 128x128 tile, BK=64, global_load_lds w=16, XOR-swizzled LDS reads.
__global__ __launch_bounds__(256) void k_gemm(const unsigned short* __restrict__ Ahi,
                                              const unsigned short* __restrict__ Alo,
                                              const unsigned short* __restrict__ Bhi,
                                              const unsigned short* __restrict__ Blo,
                                              float* __restrict__ O, int M) {
    __shared__ unsigned short lds[4][128 * 64];  // Ahi, Alo, Bhi, Blo: 16KB each
    const int tid = threadIdx.x;
    const int m0 = blockIdx.x * 128;
    const int n0 = blockIdx.y * 128;
    const int wid = tid >> 6, lane = tid & 63;
    const int wm = wid >> 1, wn = wid & 1;
    const int r16 = lane & 15, kq = lane >> 4;

    f32x4 acc[4][4];
    #pragma unroll
    for (int i = 0; i < 4; ++i)
        #pragma unroll
        for (int j = 0; j < 4; ++j) acc[i][j] = (f32x4){0.f, 0.f, 0.f, 0.f};

    for (int kt = 0; kt < 4; ++kt) {
        const int kk = kt * 64;
        // stage: chunk q -> row=q>>3, cpos=q&7; source chunk = cpos ^ (row&7)
        // (pre-swizzled global source, linear LDS dest, swizzled read)
        #pragma unroll
        for (int rnd = 0; rnd < 4; ++rnd) {
            int q = rnd * 256 + tid;
            int row = q >> 3, c = q & 7;
            int sc = c ^ (row & 7);
            size_t goffA = (size_t)(m0 + row) * HID + kk + sc * 8;
            size_t goffB = (size_t)(n0 + row) * HID + kk + sc * 8;
            gload_lds16(Ahi + goffA, &lds[0][q * 8]);
            gload_lds16(Alo + goffA, &lds[1][q * 8]);
            gload_lds16(Bhi + goffB, &lds[2][q * 8]);
            gload_lds16(Blo + goffB, &lds[3][q * 8]);
        }
        __syncthreads();
        #pragma unroll
        for (int ks = 0; ks < 2; ++ks) {
            bf16x8 ah[4], al[4], bh[4], bl[4];
            #pragma unroll
            for (int f = 0; f < 4; ++f) {
                int rowa = wm * 64 + f * 16 + r16;
                int ca = (ks * 4 + kq) ^ (rowa & 7);
                int offa = rowa * 64 + ca * 8;
                ah[f] = *(const bf16x8*)&lds[0][offa];
                al[f] = *(const bf16x8*)&lds[1][offa];
                int rowb = wn * 64 + f * 16 + r16;
                int cb = (ks * 4 + kq) ^ (rowb & 7);
                int offb = rowb * 64 + cb * 8;
                bh[f] = *(const bf16x8*)&lds[2][offb];
                bl[f] = *(const bf16x8*)&lds[3][offb];
            }
            #pragma unroll
            for (int mi = 0; mi < 4; ++mi)
                #pragma unroll
                for (int ni = 0; ni < 4; ++ni) {
                    acc[mi][ni] = __builtin_amdgcn_mfma_f32_16x16x32_bf16(ah[mi], bh[ni], acc[mi][ni], 0, 0, 0);
                    acc[mi][ni] = __builtin_amdgcn_mfma_f32_16x16x32_bf16(ah[mi], bl[ni], acc[mi][ni], 0, 0, 0);
                    acc[mi][ni] = __builtin_amdgcn_mfma_f32_16x16x32_bf16(al[mi], bh[ni], acc[mi][ni], 0, 0, 0);
                }
        }
        __syncthreads();
    }
    // C/D layout: col = lane&15, row = (lane>>4)*4 + reg  [m89-verified]
    #pragma unroll
    for (int mi = 0; mi < 4; ++mi) {
        #pragma unroll
        for (int q = 0; q < 4; ++q) {
            int row = m0 + wm * 64 + mi * 16 + kq * 4 + q;
            if (row < M) {
                #pragma unroll
                for (int ni = 0; ni < 4; ++ni) {
                    int col = n0 + wn * 64 + ni * 16 + r16;
                    O[(size_t)row * HID + col] = acc[mi][ni][q];
                }
            }
        }
    }
}

// ---------------- attention logits ----------------
__global__ void k_scores(const float* __restrict__ H, const float* __restrict__ a_src,
                         const float* __restrict__ a_dst, float* __restrict__ es,
                         float* __restrict__ ed) {
    int w = (blockIdx.x * blockDim.x + threadIdx.x) >> 6;
    if (w >= NN) return;
    int lane = threadIdx.x & 63;
    int head = lane >> 3;
    int sub = lane & 7;
    float4 h = *(const float4*)(H + (size_t)w * HID + lane * 4);
    float4 as4 = *(const float4*)(a_src + head * 32 + sub * 4);
    float4 ad4 = *(const float4*)(a_dst + head * 32 + sub * 4);
    float ps = h.x * as4.x + h.y * as4.y + h.z * as4.z + h.w * as4.w;
    float pd = h.x * ad4.x + h.y * ad4.y + h.z * ad4.z + h.w * ad4.w;
    #pragma unroll
    for (int off = 1; off < 8; off <<= 1) {
        ps += __shfl_xor(ps, off, 64);
        pd += __shfl_xor(pd, off, 64);
    }
    if (sub == 0) {
        es[w * NH + head] = ps;
        ed[w * NH + head] = pd;
    }
}

// ---------------- segment softmax + aggregate + bias + relu -> hi/lo ----------------
__global__ __launch_bounds__(256) void k_aggregate(const float* __restrict__ H,
                                                   const float* __restrict__ es,
                                                   const float* __restrict__ ed,
                                                   const int* __restrict__ indptr,
                                                   const int* __restrict__ srcs,
                                                   const float* __restrict__ bias,
                                                   unsigned short* __restrict__ Phi,
                                                   unsigned short* __restrict__ Plo) {
    int node = (blockIdx.x * blockDim.x + threadIdx.x) >> 6;
    if (node >= NN) return;
    int lane = threadIdx.x & 63;
    int head = lane >> 3;
    int b0 = indptr[node], e0 = indptr[node + 1];
    float edv = ed[node * NH + head];
    // pass 1: segment max (unroll 4)
    float m = -FLT_MAX;
    int j = b0;
    for (; j + 3 < e0; j += 4) {
        int s0 = srcs[j], s1 = srcs[j + 1], s2 = srcs[j + 2], s3 = srcs[j + 3];
        float e0v = es[s0 * NH + head] + edv;
        float e1v = es[s1 * NH + head] + edv;
        float e2v = es[s2 * NH + head] + edv;
        float e3v = es[s3 * NH + head] + edv;
        e0v = (e0v > 0.f) ? e0v : 0.2f * e0v;
        e1v = (e1v > 0.f) ? e1v : 0.2f * e1v;
        e2v = (e2v > 0.f) ? e2v : 0.2f * e2v;
        e3v = (e3v > 0.f) ? e3v : 0.2f * e3v;
        m = fmaxf(m, fmaxf(fmaxf(e0v, e1v), fmaxf(e2v, e3v)));
    }
    for (; j < e0; ++j) {
        int s = srcs[j];
        float e = es[s * NH + head] + edv;
        e = (e > 0.f) ? e : 0.2f * e;
        m = fmaxf(m, e);
    }
    // pass 2: weighted gather (unroll 2, dual accumulators for MLP)
    float sumA = 0.f, sumB = 0.f;
    float ax = 0.f, ay = 0.f, az = 0.f, aw = 0.f;
    float bx = 0.f, by = 0.f, bz = 0.f, bw = 0.f;
    j = b0;
    for (; j + 1 < e0; j += 2) {
        int s0 = srcs[j], s1 = srcs[j + 1];
        const float4 h0 = *(const float4*)(H + (size_t)s0 * HID + lane * 4);
        const float4 h1 = *(const float4*)(H + (size_t)s1 * HID + lane * 4);
        float e0v = es[s0 * NH + head] + edv;
        float e1v = es[s1 * NH + head] + edv;
        e0v = (e0v > 0.f) ? e0v : 0.2f * e0v;
        e1v = (e1v > 0.f) ? e1v : 0.2f * e1v;
        float w0 = expf(e0v - m);
        float w1 = expf(e1v - m);
        sumA += w0; sumB += w1;
        ax = fmaf(w0, h0.x, ax); ay = fmaf(w0, h0.y, ay);
        az = fmaf(w0, h0.z, az); aw = fmaf(w0, h0.w, aw);
        bx = fmaf(w1, h1.x, bx); by = fmaf(w1, h1.y, by);
        bz = fmaf(w1, h1.z, bz); bw = fmaf(w1, h1.w, bw);
    }
    if (j < e0) {
        int s = srcs[j];
        const float4 h0 = *(const float4*)(H + (size_t)s * HID + lane * 4);
        float e = es[s * NH + head] + edv;
        e = (e > 0.f) ? e : 0.2f * e;
        float w0 = expf(e - m);
        sumA += w0;
        ax = fmaf(w0, h0.x, ax); ay = fmaf(w0, h0.y, ay);
        az = fmaf(w0, h0.z, az); aw = fmaf(w0, h0.w, aw);
    }
    float inv = 1.f / (sumA + sumB + 1e-16f);
    float4 bv = *(const float4*)(bias + lane * 4);
    float o[4];
    o[0] = fmaxf(fmaf(ax + bx, inv, bv.x), 0.f);
    o[1] = fmaxf(fmaf(ay + by, inv, bv.y), 0.f);
    o[2] = fmaxf(fmaf(az + bz, inv, bv.z), 0.f);
    o[3] = fmaxf(fmaf(aw + bw, inv, bv.w), 0.f);
    ushort4 hv, lv;
    f2hilo(o[0], hv.x, lv.x); f2hilo(o[1], hv.y, lv.y);
    f2hilo(o[2], hv.z, lv.z); f2hilo(o[3], hv.w, lv.w);
    *(ushort4*)(Phi + (size_t)node * HID + lane * 4) = hv;
    *(ushort4*)(Plo + (size_t)node * HID + lane * 4) = lv;
}

// ---------------- per-graph max pool + linear head ----------------
__global__ void k_pool(const unsigned short* __restrict__ Phi,
                       const unsigned short* __restrict__ Plo,
                       const int* __restrict__ starts,
                       const float* __restrict__ fw, const float* __restrict__ fb,
                       float* __restrict__ out) {
    int g = (blockIdx.x * blockDim.x + threadIdx.x) >> 6;
    if (g >= GG) return;
    int lane = threadIdx.x & 63;
    int s = starts[g], e = starts[g + 1];
    float mx0 = -FLT_MAX, mx1 = -FLT_MAX, mx2 = -FLT_MAX, mx3 = -FLT_MAX;
    for (int n = s; n < e; ++n) {
        ushort4 hv = *(const ushort4*)(Phi + (size_t)n * HID + lane * 4);
        ushort4 lv = *(const ushort4*)(Plo + (size_t)n * HID + lane * 4);
        mx0 = fmaxf(mx0, bf2f(hv.x) + bf2f(lv.x));
        mx1 = fmaxf(mx1, bf2f(hv.y) + bf2f(lv.y));
        mx2 = fmaxf(mx2, bf2f(hv.z) + bf2f(lv.z));
        mx3 = fmaxf(mx3, bf2f(hv.w) + bf2f(lv.w));
    }
    float4 w = *(const float4*)(fw + lane * 4);
    float t = mx0 * w.x + mx1 * w.y + mx2 * w.z + mx3 * w.w;
    #pragma unroll
    for (int off = 32; off >= 1; off >>= 1) t += __shfl_xor(t, off, 64);
    if (lane == 0) out[g] = t + fb[0];
}

// ---------------- launcher ----------------
extern "C" void kernel_launch(void* const* d_in, const int* in_sizes, int n_in,
                              void* d_out, int out_size, void* d_ws, size_t ws_size,
                              hipStream_t stream) {
    const int* x_ids = (const int*)d_in[0];
    const int* eidx  = (const int*)d_in[1];
    const int* batch = (const int*)d_in[2];
    const float* emb = (const float*)d_in[3];
    const float* fw  = (const float*)d_in[4];
    const float* fb  = (const float*)d_in[5];
    const float* Wl[5], *asl[5], *adl[5], *bl[5];
    for (int l = 0; l < 5; ++l) {
        Wl[l]  = (const float*)d_in[6 + 4 * l];
        asl[l] = (const float*)d_in[7 + 4 * l];
        adl[l] = (const float*)d_in[8 + 4 * l];
        bl[l]  = (const float*)d_in[9 + 4 * l];
    }

    char* ws = (char*)d_ws;
    size_t off = 0;
    auto alloc = [&](size_t bytes) {
        void* p = ws + off;
        off = (off + bytes + 255) & ~(size_t)255;
        return p;
    };
    unsigned short* Phi = (unsigned short*)alloc((size_t)NP * HID * 2);
    unsigned short* Plo = (unsigned short*)alloc((size_t)NP * HID * 2);
    float* Q    = (float*)alloc((size_t)NN * HID * 4);
    unsigned short* Whi = (unsigned short*)alloc((size_t)5 * HID * HID * 2);
    unsigned short* Wlo = (unsigned short*)alloc((size_t)5 * HID * HID * 2);
    float* es   = (float*)alloc((size_t)NN * NH * 4);
    float* ed   = (float*)alloc((size_t)NN * NH * 4);
    int* cnt    = (int*)alloc((size_t)NN * 4);
    int* cursor = (int*)alloc((size_t)NN * 4);
    int* indptr = (int*)alloc((size_t)(NN + 1) * 4);
    int* srcs   = (int*)alloc((size_t)EP * 4);
    int* starts = (int*)alloc((size_t)(GG + 1) * 4);
    (void)ws_size; (void)in_sizes; (void)n_in; (void)out_size;

    hipMemsetAsync(cnt, 0, (size_t)NN * 4, stream);
    hipMemsetAsync(cursor, 0, (size_t)NN * 4, stream);

    k_hist<<<(EP + 255) / 256, 256, 0, stream>>>(eidx + EE, cnt);
    k_scan<<<1, 1024, 0, stream>>>(cnt, indptr);
    k_fill<<<(EP + 255) / 256, 256, 0, stream>>>(eidx, eidx + EE, indptr, cursor, srcs);
    k_sortseg<<<(NN + 255) / 256, 256, 0, stream>>>(srcs, indptr);
    k_starts<<<(NN + 255) / 256, 256, 0, stream>>>(batch, starts);
    k_wconv<<<dim3(HID * HID / 256, 5), 256, 0, stream>>>(Wl[0], Wl[1], Wl[2], Wl[3], Wl[4], Whi, Wlo);
    k_embed<<<NN / 4, 256, 0, stream>>>(x_ids, emb, Phi, Plo);

    for (int l = 0; l < 5; ++l) {
        dim3 gg(NP / 128, HID / 128);
        k_gemm<<<gg, 256, 0, stream>>>(Phi, Plo, Whi + (size_t)l * HID * HID,
                                       Wlo + (size_t)l * HID * HID, Q, NN);
        k_scores<<<NN / 4, 256, 0, stream>>>(Q, asl[l], adl[l], es, ed);
        k_aggregate<<<NN / 4, 256, 0, stream>>>(Q, es, ed, indptr, srcs, bl[l], Phi, Plo);
    }
    k_pool<<<GG / 4, 256, 0, stream>>>(Phi, Plo, starts, fw, fb, (float*)d_out);
}